// Round 4
// baseline (663.453 us; speedup 1.0000x reference)
//
#include <hip/hip_runtime.h>
#include <hip/hip_bf16.h>

typedef unsigned short u16;

#define NE 3072      // edges
#define DM 128       // model dim
#define NH 8         // heads
#define HD 16        // head dim
#define NL 3         // layers
#define NR 64        // rbf
#define FF 512       // ffn dim
#define CUT 10.0f
#define CAP 96       // max neighbors per row (counts ~12 mean; huge safety margin)

// ---------------- prep: meta, h=ef, x=ec, rbf ----------------
__global__ __launch_bounds__(64)
void prep_kernel(const float* __restrict__ ef, const float* __restrict__ ec,
                 const int* __restrict__ eidx, const float* __restrict__ nc,
                 const int* __restrict__ bids,
                 float* __restrict__ h, float* __restrict__ x,
                 float* __restrict__ rbf, int4* __restrict__ meta) {
    int e = blockIdx.x, lane = threadIdx.x;
    int s = eidx[e], d = eidx[NE + e];
    if (lane == 0) meta[e] = make_int4(s, d, bids[s], bids[d]);
    h[e * DM + lane]      = ef[e * DM + lane];
    h[e * DM + 64 + lane] = ef[e * DM + 64 + lane];
    if (lane < 3) x[e * 3 + lane] = ec[e * 3 + lane];
    float dx = nc[d * 3 + 0] - nc[s * 3 + 0];
    float dy = nc[d * 3 + 1] - nc[s * 3 + 1];
    float dz = nc[d * 3 + 2] - nc[s * 3 + 2];
    float dist = sqrtf(dx * dx + dy * dy + dz * dz);
    float t = fminf(fmaxf(dist / CUT, 0.f), 1.f);
    float fc = 0.5f * (cosf(3.14159265358979f * t) + 1.f);
    float width = CUT / NR;                       // 10/64
    float center = (CUT * lane) / (NR - 1);       // linspace(0,10,64)
    float u = (dist - center) / width;
    rbf[e * NR + lane] = expf(-u * u) * fc;
}

// ---------------- build neighbor lists (masks are layer-invariant) ----------------
__global__ __launch_bounds__(64)
void build_lists(const int4* __restrict__ meta,
                 u16* __restrict__ idx_a, int* __restrict__ cnt_a,
                 u16* __restrict__ idx_e, int* __restrict__ cnt_e) {
    __shared__ int ca, ce;
    __shared__ u16 ba[CAP], be[CAP];
    int i = blockIdx.x, lane = threadIdx.x;
    if (lane == 0) { ca = 0; ce = 0; }
    __syncthreads();
    int4 mi = meta[i];
    for (int j = lane; j < NE; j += 64) {
        int4 mj = meta[j];
        bool intra_b = (mi.z == mj.z) && (mi.w == mj.w);
        bool share = (mi.x == mj.x) || (mi.x == mj.y) ||
                     (mi.y == mj.x) || (mi.y == mj.y);
        bool oka = intra_b || (i == j);
        bool oke = (share && !intra_b) || (i == j);
        if (oka) { int p = atomicAdd(&ca, 1); if (p < CAP) ba[p] = (u16)j; }
        if (oke) { int p = atomicAdd(&ce, 1); if (p < CAP) be[p] = (u16)j; }
    }
    __syncthreads();
    int na = min(ca, CAP), ne_ = min(ce, CAP);
    if (lane == 0) { cnt_a[i] = na; cnt_e[i] = ne_; }
    for (int p = lane; p < na; p += 64) idx_a[i * CAP + p] = ba[p];
    for (int p = lane; p < ne_; p += 64) idx_e[i * CAP + p] = be[p];
}

// ---------------- rbf @ Wrbf[l], accumulate into h ----------------
__global__ __launch_bounds__(128)
void rbf_gemm(const float* __restrict__ rbf, const float* __restrict__ W,
              float* __restrict__ h) {
    __shared__ float a_s[NR];
    int row = blockIdx.x, t = threadIdx.x;
    if (t < NR) a_s[t] = rbf[row * NR + t];
    __syncthreads();
    float acc = 0.f;
#pragma unroll
    for (int k = 0; k < NR; k++) acc += a_s[k] * W[k * DM + t];
    h[row * DM + t] += acc;
}

// ---------------- fused q,k,v projection ----------------
__global__ __launch_bounds__(128)
void gemm_qkv(const float* __restrict__ A, const float* __restrict__ Bq,
              const float* __restrict__ Bk, const float* __restrict__ Bv,
              float* __restrict__ q, float* __restrict__ k, float* __restrict__ v) {
    __shared__ float a_s[DM];
    int row = blockIdx.x, t = threadIdx.x;
    a_s[t] = A[row * DM + t];
    __syncthreads();
    float aq = 0.f, ak = 0.f, av = 0.f;
#pragma unroll 4
    for (int kk = 0; kk < DM; kk++) {
        float a = a_s[kk];
        aq += a * Bq[kk * DM + t];
        ak += a * Bk[kk * DM + t];
        av += a * Bv[kk * DM + t];
    }
    q[row * DM + t] = aq;
    k[row * DM + t] = ak;
    v[row * DM + t] = av;
}

// ---------------- masked attention via neighbor lists ----------------
// one wave per (head, query-row); V augmented with x (3 dims) for INTRA
template <bool INTRA>
__global__ __launch_bounds__(256)
void attn_kernel(const float* __restrict__ q, const float* __restrict__ k,
                 const float* __restrict__ v, const float* __restrict__ xw,
                 const u16* __restrict__ idx, const int* __restrict__ cnt,
                 float* __restrict__ o, float* __restrict__ px_part) {
    int gwave = (blockIdx.x * 256 + threadIdx.x) >> 6;
    int lane = threadIdx.x & 63;
    int head = gwave & (NH - 1);
    int i = gwave >> 3;

    float qreg[HD];
    const float* qp = q + i * DM + head * HD;
#pragma unroll
    for (int d = 0; d < HD; d++) qreg[d] = qp[d];

    int n = cnt[i];
    float m = -1e30f, l = 0.f;
    float acc[HD + 3];
#pragma unroll
    for (int d = 0; d < HD + 3; d++) acc[d] = 0.f;

    for (int p = lane; p < n; p += 64) {
        int j = idx[i * CAP + p];
        const float* kp = k + j * DM + head * HD;
        float s = 0.f;
#pragma unroll
        for (int d = 0; d < HD; d++) s += qreg[d] * kp[d];
        s *= 0.25f;  // 1/sqrt(16)
        if (s > m) {
            float corr = __expf(m - s);
            m = s;
            l *= corr;
#pragma unroll
            for (int d = 0; d < HD + 3; d++) acc[d] *= corr;
        }
        float pw = __expf(s - m);
        l += pw;
        const float* vp = v + j * DM + head * HD;
#pragma unroll
        for (int d = 0; d < HD; d++) acc[d] += pw * vp[d];
        if (INTRA) {
            const float* xp = xw + j * 3;
#pragma unroll
            for (int c = 0; c < 3; c++) acc[HD + c] += pw * xp[c];
        }
    }
    // merge lanes: global max, rescale, butterfly sums
    float mAll = m;
#pragma unroll
    for (int off = 32; off; off >>= 1) mAll = fmaxf(mAll, __shfl_xor(mAll, off));
    float cf = __expf(m - mAll);
    l *= cf;
#pragma unroll
    for (int d = 0; d < HD + 3; d++) acc[d] *= cf;
#pragma unroll
    for (int off = 32; off; off >>= 1) {
        l += __shfl_xor(l, off);
#pragma unroll
        for (int d = 0; d < HD + 3; d++) acc[d] += __shfl_xor(acc[d], off);
    }
    if (lane == 0) {
        float inv = 1.f / l;
        float* op = o + i * DM + head * HD;
#pragma unroll
        for (int d = 0; d < HD; d++) op[d] = acc[d] * inv;
        if (INTRA) {
            float* pp = px_part + (head * NE + i) * 3;
            pp[0] = acc[HD + 0] * inv;
            pp[1] = acc[HD + 1] * inv;
            pp[2] = acc[HD + 2] * inv;
        }
    }
}

// ---------------- fused: o @ Wo + residual + LayerNorm (in place on h) ----------------
__global__ __launch_bounds__(128)
void wo_add_ln(const float* __restrict__ o, const float* __restrict__ Wo,
               float* __restrict__ h, const float* __restrict__ g,
               const float* __restrict__ b) {
    __shared__ float o_s[DM];
    __shared__ float red[2];
    int row = blockIdx.x, t = threadIdx.x;
    o_s[t] = o[row * DM + t];
    __syncthreads();
    float acc = 0.f;
#pragma unroll 4
    for (int kk = 0; kk < DM; kk++) acc += o_s[kk] * Wo[kk * DM + t];
    float z = h[row * DM + t] + acc;
    float s = z;
#pragma unroll
    for (int off = 32; off; off >>= 1) s += __shfl_xor(s, off);
    if ((t & 63) == 0) red[t >> 6] = s;
    __syncthreads();
    float mean = (red[0] + red[1]) * (1.f / DM);
    __syncthreads();
    float d = z - mean;
    float vs = d * d;
#pragma unroll
    for (int off = 32; off; off >>= 1) vs += __shfl_xor(vs, off);
    if ((t & 63) == 0) red[t >> 6] = vs;
    __syncthreads();
    float var = (red[0] + red[1]) * (1.f / DM);
    float inv = rsqrtf(var + 1e-5f);
    h[row * DM + t] = d * inv * g[t] + b[t];
}

// ---------------- fused FFN: silu(h@W1+b1)@W2+b2 + residual + LN ----------------
__global__ __launch_bounds__(128)
void ffn_add_ln(const float* __restrict__ W1, const float* __restrict__ b1,
                const float* __restrict__ W2, const float* __restrict__ b2,
                float* __restrict__ h, const float* __restrict__ g,
                const float* __restrict__ bia) {
    __shared__ float h_s[DM];
    __shared__ float u_s[FF];
    __shared__ float red[2];
    int row = blockIdx.x, t = threadIdx.x;
    h_s[t] = h[row * DM + t];
    __syncthreads();
#pragma unroll
    for (int j = 0; j < FF / 128; j++) {
        int col = t + j * 128;
        float acc = b1[col];
#pragma unroll 4
        for (int kk = 0; kk < DM; kk++) acc += h_s[kk] * W1[kk * FF + col];
        u_s[col] = acc / (1.f + __expf(-acc));   // silu
    }
    __syncthreads();
    float acc = b2[t];
#pragma unroll 4
    for (int kk = 0; kk < FF; kk++) acc += u_s[kk] * W2[kk * DM + t];
    float z = h_s[t] + acc;
    float s = z;
#pragma unroll
    for (int off = 32; off; off >>= 1) s += __shfl_xor(s, off);
    if ((t & 63) == 0) red[t >> 6] = s;
    __syncthreads();
    float mean = (red[0] + red[1]) * (1.f / DM);
    __syncthreads();
    float d = z - mean;
    float vs = d * d;
#pragma unroll
    for (int off = 32; off; off >>= 1) vs += __shfl_xor(vs, off);
    if ((t & 63) == 0) red[t >> 6] = vs;
    __syncthreads();
    float var = (red[0] + red[1]) * (1.f / DM);
    float inv = rsqrtf(var + 1e-5f);
    h[row * DM + t] = d * inv * g[t] + bia[t];
}

// ---------------- equivariant coordinate update ----------------
__global__ __launch_bounds__(64)
void coord_update(const float* __restrict__ h, const float* __restrict__ Wc,
                  const float* __restrict__ bc, const float* __restrict__ px_part,
                  float* __restrict__ x) {
    int row = blockIdx.x, lane = threadIdx.x;
    float s = h[row * DM + lane] * Wc[lane] +
              h[row * DM + 64 + lane] * Wc[64 + lane];
#pragma unroll
    for (int off = 32; off; off >>= 1) s += __shfl_xor(s, off);
    float gate = tanhf(s + bc[0]);
    if (lane < 3) {
        float px = 0.f;
#pragma unroll
        for (int hh = 0; hh < NH; hh++) px += px_part[(hh * NE + row) * 3 + lane];
        px *= 0.125f;
        float xv = x[row * 3 + lane];
        x[row * 3 + lane] = xv + gate * (xv - px);
    }
}

// ---------------- write outputs (h then x), FLOAT32 ----------------
__global__ void finalize_kernel(const float* __restrict__ h, const float* __restrict__ x,
                                float* __restrict__ out) {
    int i = blockIdx.x * blockDim.x + threadIdx.x;
    if (i < NE * DM) out[i] = h[i];
    else if (i < NE * DM + NE * 3) out[i] = x[i - NE * DM];
}

extern "C" void kernel_launch(void* const* d_in, const int* in_sizes, int n_in,
                              void* d_out, int out_size, void* d_ws, size_t ws_size,
                              hipStream_t stream) {
    const float* ef   = (const float*)d_in[0];
    const float* ec   = (const float*)d_in[1];
    const int*   eidx = (const int*)d_in[2];
    const float* nc   = (const float*)d_in[3];
    const int*   bids = (const int*)d_in[4];
    const float* Wq_a = (const float*)d_in[5];
    const float* Wk_a = (const float*)d_in[6];
    const float* Wv_a = (const float*)d_in[7];
    const float* Wo_a = (const float*)d_in[8];
    const float* Wq_e = (const float*)d_in[9];
    const float* Wk_e = (const float*)d_in[10];
    const float* Wv_e = (const float*)d_in[11];
    const float* Wo_e = (const float*)d_in[12];
    const float* W1   = (const float*)d_in[13];
    const float* b1   = (const float*)d_in[14];
    const float* W2   = (const float*)d_in[15];
    const float* b2   = (const float*)d_in[16];
    const float* ln1g = (const float*)d_in[17];
    const float* ln1b = (const float*)d_in[18];
    const float* ln2g = (const float*)d_in[19];
    const float* ln2b = (const float*)d_in[20];
    const float* ln3g = (const float*)d_in[21];
    const float* ln3b = (const float*)d_in[22];
    const float* Wrbf = (const float*)d_in[23];
    const float* Wc   = (const float*)d_in[24];
    const float* bc   = (const float*)d_in[25];
    float* out = (float*)d_out;

    // workspace carve — critical small buffers FIRST (total ~9.6 MB)
    char* w = (char*)d_ws;
    auto carve = [&](size_t bytes) { char* p = w; w += ((bytes + 255) / 256) * 256; return p; };
    int4*  meta  = (int4*)carve((size_t)NE * 16);
    float* x     = (float*)carve((size_t)NE * 3 * 4);
    float* pxp   = (float*)carve((size_t)NH * NE * 3 * 4);
    int*   cnt_a = (int*)carve((size_t)NE * 4);
    int*   cnt_e = (int*)carve((size_t)NE * 4);
    u16*   idx_a = (u16*)carve((size_t)NE * CAP * 2);
    u16*   idx_e = (u16*)carve((size_t)NE * CAP * 2);
    float* rbf   = (float*)carve((size_t)NE * NR * 4);
    float* h     = (float*)carve((size_t)NE * DM * 4);
    float* o     = (float*)carve((size_t)NE * DM * 4);
    float* q     = (float*)carve((size_t)NE * DM * 4);
    float* k     = (float*)carve((size_t)NE * DM * 4);
    float* v     = (float*)carve((size_t)NE * DM * 4);

    prep_kernel<<<NE, 64, 0, stream>>>(ef, ec, eidx, nc, bids, h, x, rbf, meta);
    build_lists<<<NE, 64, 0, stream>>>(meta, idx_a, cnt_a, idx_e, cnt_e);

    for (int l = 0; l < NL; l++) {
        rbf_gemm<<<NE, 128, 0, stream>>>(rbf, Wrbf + (size_t)l * NR * DM, h);

        // intra MHA
        gemm_qkv<<<NE, 128, 0, stream>>>(h, Wq_a + l * DM * DM, Wk_a + l * DM * DM,
                                         Wv_a + l * DM * DM, q, k, v);
        attn_kernel<true><<<(NH * NE) / 4, 256, 0, stream>>>(q, k, v, x, idx_a, cnt_a, o, pxp);
        wo_add_ln<<<NE, 128, 0, stream>>>(o, Wo_a + l * DM * DM, h, ln1g + l * DM, ln1b + l * DM);

        // inter MHA
        gemm_qkv<<<NE, 128, 0, stream>>>(h, Wq_e + l * DM * DM, Wk_e + l * DM * DM,
                                         Wv_e + l * DM * DM, q, k, v);
        attn_kernel<false><<<(NH * NE) / 4, 256, 0, stream>>>(q, k, v, x, idx_e, cnt_e, o, nullptr);
        wo_add_ln<<<NE, 128, 0, stream>>>(o, Wo_e + l * DM * DM, h, ln2g + l * DM, ln2b + l * DM);

        // FFN
        ffn_add_ln<<<NE, 128, 0, stream>>>(W1 + (size_t)l * DM * FF, b1 + l * FF,
                                           W2 + (size_t)l * FF * DM, b2 + l * DM,
                                           h, ln3g + l * DM, ln3b + l * DM);

        // coordinate update
        coord_update<<<NE, 64, 0, stream>>>(h, Wc + l * DM, bc + l, pxp, x);
    }

    int total = NE * DM + NE * 3;
    finalize_kernel<<<(total + 255) / 256, 256, 0, stream>>>(h, x, out);
}

// Round 5
// 404.971 us; speedup vs baseline: 1.6383x; 1.6383x over previous
//
#include <hip/hip_runtime.h>
#include <hip/hip_bf16.h>

typedef unsigned short u16;
typedef __attribute__((ext_vector_type(4))) float f32x4;
typedef __attribute__((ext_vector_type(8))) short bf16x8;

#define NE 3072
#define DM 128
#define NH 8
#define HD 16
#define NL 3
#define NR 64
#define FF 512
#define CUT 10.0f
#define CAP 96

// per-layer packed-weight element counts / offsets (bf16 elems)
#define PK_QKV_A 0
#define PK_WO_A  49152
#define PK_QKV_E 65536
#define PK_WO_E  114688
#define PK_W1    131072
#define PK_W2    196608
#define PK_WRBF  262144
#define PK_LAYER 270336

__device__ __forceinline__ short f2b(float f) {
    unsigned u = __float_as_uint(f);
    unsigned r = (u + 0x7FFFu + ((u >> 16) & 1u)) >> 16;
    return (short)r;
}

// load A fragment: row-major f32 A, lane l -> row (l&15), k = kbase + 8*(l>>4) + i
__device__ __forceinline__ bf16x8 load_a(const float* A, int rowoff, int kbase) {
    const float4* p = reinterpret_cast<const float4*>(A + rowoff + kbase);
    float4 f0 = p[0], f1 = p[1];
    bf16x8 r;
    r[0] = f2b(f0.x); r[1] = f2b(f0.y); r[2] = f2b(f0.z); r[3] = f2b(f0.w);
    r[4] = f2b(f1.x); r[5] = f2b(f1.y); r[6] = f2b(f1.z); r[7] = f2b(f1.w);
    return r;
}

// ---------------- pack all weights into bf16 fragment-linear layout ----------------
struct WSrc { const float* W[11]; };

__global__ __launch_bounds__(256)
void pack_w(WSrc ws, short* __restrict__ dst) {
    int gid = blockIdx.x * 256 + threadIdx.x;
    if (gid >= NL * PK_LAYER) return;
    int layer = gid / PK_LAYER, e = gid % PK_LAYER;
    int kind, off, K, N;
    if (e < 49152)       { kind = e / 16384;            off = e % 16384;      K = 128; N = 128; }
    else if (e < 65536)  { kind = 3;                    off = e - 49152;      K = 128; N = 128; }
    else if (e < 114688) { kind = 4 + (e - 65536) / 16384; off = (e - 65536) % 16384; K = 128; N = 128; }
    else if (e < 131072) { kind = 7;                    off = e - 114688;     K = 128; N = 128; }
    else if (e < 196608) { kind = 8;                    off = e - 131072;     K = 128; N = 512; }
    else if (e < 262144) { kind = 9;                    off = e - 196608;     K = 512; N = 128; }
    else                 { kind = 10;                   off = e - 262144;     K = 64;  N = 128; }
    int i = off & 7, lane = (off >> 3) & 63, ft = off >> 9;
    int KT = K >> 5;
    int kt = ft % KT, nt = ft / KT;
    int n = nt * 16 + (lane & 15);
    int k = kt * 32 + 8 * (lane >> 4) + i;
    const float* W = ws.W[kind] + (size_t)layer * K * N;
    dst[gid] = f2b(W[k * N + n]);
}

// ---------------- prep: meta, h=ef, x=ec, rbf ----------------
__global__ __launch_bounds__(64)
void prep_kernel(const float* __restrict__ ef, const float* __restrict__ ec,
                 const int* __restrict__ eidx, const float* __restrict__ nc,
                 const int* __restrict__ bids,
                 float* __restrict__ h, float* __restrict__ x,
                 float* __restrict__ rbf, int4* __restrict__ meta) {
    int e = blockIdx.x, lane = threadIdx.x;
    int s = eidx[e], d = eidx[NE + e];
    if (lane == 0) meta[e] = make_int4(s, d, bids[s], bids[d]);
    h[e * DM + lane]      = ef[e * DM + lane];
    h[e * DM + 64 + lane] = ef[e * DM + 64 + lane];
    if (lane < 3) x[e * 3 + lane] = ec[e * 3 + lane];
    float dx = nc[d * 3 + 0] - nc[s * 3 + 0];
    float dy = nc[d * 3 + 1] - nc[s * 3 + 1];
    float dz = nc[d * 3 + 2] - nc[s * 3 + 2];
    float dist = sqrtf(dx * dx + dy * dy + dz * dz);
    float t = fminf(fmaxf(dist / CUT, 0.f), 1.f);
    float fc = 0.5f * (cosf(3.14159265358979f * t) + 1.f);
    float width = CUT / NR;
    float center = (CUT * lane) / (NR - 1);
    float u = (dist - center) / width;
    rbf[e * NR + lane] = expf(-u * u) * fc;
}

// ---------------- build neighbor lists ----------------
__global__ __launch_bounds__(64)
void build_lists(const int4* __restrict__ meta,
                 u16* __restrict__ idx_a, int* __restrict__ cnt_a,
                 u16* __restrict__ idx_e, int* __restrict__ cnt_e) {
    __shared__ int ca, ce;
    __shared__ u16 ba[CAP], be[CAP];
    int i = blockIdx.x, lane = threadIdx.x;
    if (lane == 0) { ca = 0; ce = 0; }
    __syncthreads();
    int4 mi = meta[i];
    for (int j = lane; j < NE; j += 64) {
        int4 mj = meta[j];
        bool intra_b = (mi.z == mj.z) && (mi.w == mj.w);
        bool share = (mi.x == mj.x) || (mi.x == mj.y) ||
                     (mi.y == mj.x) || (mi.y == mj.y);
        bool oka = intra_b || (i == j);
        bool oke = (share && !intra_b) || (i == j);
        if (oka) { int p = atomicAdd(&ca, 1); if (p < CAP) ba[p] = (u16)j; }
        if (oke) { int p = atomicAdd(&ce, 1); if (p < CAP) be[p] = (u16)j; }
    }
    __syncthreads();
    int na = min(ca, CAP), ne_ = min(ce, CAP);
    if (lane == 0) { cnt_a[i] = na; cnt_e[i] = ne_; }
    for (int p = lane; p < na; p += 64) idx_a[i * CAP + p] = ba[p];
    for (int p = lane; p < ne_; p += 64) idx_e[i * CAP + p] = be[p];
}

// ---------------- generic MFMA GEMM: block = 4 waves, wave = 16 rows x 128 cols ----------------
// EPI: 0 = accumulate into out0 (h += D)
//      1 = qkv split: write D to q/k/v selected by blockIdx.y
//      2 = residual + LayerNorm: h = LN(hres + D) * g + b
template <int KT, int EPI>
__global__ __launch_bounds__(256)
void gemm_mfma(const float* __restrict__ A, const short* __restrict__ Bp,
               float* out0, const float* hres,
               const float* __restrict__ g, const float* __restrict__ b,
               float* __restrict__ q, float* __restrict__ k2, float* __restrict__ v) {
    const int K = KT * 32;
    int w = threadIdx.x >> 6, l = threadIdx.x & 63;
    int m0 = blockIdx.x * 64 + w * 16;
    int arow = m0 + (l & 15);
    const short* Bsec = Bp + (size_t)blockIdx.y * 8 * KT * 512;

    f32x4 acc[8];
#pragma unroll
    for (int t = 0; t < 8; t++) acc[t] = {0.f, 0.f, 0.f, 0.f};

#pragma unroll
    for (int kt = 0; kt < KT; kt++) {
        bf16x8 av = load_a(A, arow * K, kt * 32 + 8 * (l >> 4));
#pragma unroll
        for (int t = 0; t < 8; t++) {
            bf16x8 bv = *reinterpret_cast<const bf16x8*>(Bsec + (t * KT + kt) * 512 + l * 8);
            acc[t] = __builtin_amdgcn_mfma_f32_16x16x32_bf16(av, bv, acc[t], 0, 0, 0);
        }
    }

    int R4 = 4 * (l >> 4), c0 = l & 15;
    if (EPI == 0) {
#pragma unroll
        for (int t = 0; t < 8; t++)
#pragma unroll
            for (int r = 0; r < 4; r++)
                out0[(m0 + R4 + r) * DM + 16 * t + c0] += acc[t][r];
    } else if (EPI == 1) {
        float* outs = (blockIdx.y == 0) ? q : (blockIdx.y == 1) ? k2 : v;
#pragma unroll
        for (int t = 0; t < 8; t++)
#pragma unroll
            for (int r = 0; r < 4; r++)
                outs[(m0 + R4 + r) * DM + 16 * t + c0] = acc[t][r];
    } else {
        // z = D + hres; LN over 128 cols of each row
#pragma unroll
        for (int t = 0; t < 8; t++)
#pragma unroll
            for (int r = 0; r < 4; r++)
                acc[t][r] += hres[(m0 + R4 + r) * DM + 16 * t + c0];
        float s[4];
#pragma unroll
        for (int r = 0; r < 4; r++) {
            s[r] = 0.f;
#pragma unroll
            for (int t = 0; t < 8; t++) s[r] += acc[t][r];
        }
#pragma unroll
        for (int m = 1; m < 16; m <<= 1)
#pragma unroll
            for (int r = 0; r < 4; r++) s[r] += __shfl_xor(s[r], m);
        float mean[4];
#pragma unroll
        for (int r = 0; r < 4; r++) mean[r] = s[r] * (1.f / DM);
        float vs[4];
#pragma unroll
        for (int r = 0; r < 4; r++) {
            vs[r] = 0.f;
#pragma unroll
            for (int t = 0; t < 8; t++) {
                float d = acc[t][r] - mean[r];
                vs[r] += d * d;
            }
        }
#pragma unroll
        for (int m = 1; m < 16; m <<= 1)
#pragma unroll
            for (int r = 0; r < 4; r++) vs[r] += __shfl_xor(vs[r], m);
        float inv[4];
#pragma unroll
        for (int r = 0; r < 4; r++) inv[r] = rsqrtf(vs[r] * (1.f / DM) + 1e-5f);
#pragma unroll
        for (int t = 0; t < 8; t++) {
            int cc = 16 * t + c0;
            float gg = g[cc], bbv = b[cc];
#pragma unroll
            for (int r = 0; r < 4; r++)
                out0[(m0 + R4 + r) * DM + cc] = (acc[t][r] - mean[r]) * inv[r] * gg + bbv;
        }
    }
}

// ---------------- fused FFN: u = silu(h@W1+b1); z = u@W2+b2+h; h = LN(z) ----------------
__global__ __launch_bounds__(256)
void ffn_mfma(float* h, const short* __restrict__ pW1, const short* __restrict__ pW2,
              const float* __restrict__ b1, const float* __restrict__ b2,
              const float* __restrict__ g, const float* __restrict__ bb) {
    __shared__ short u_s[4 * 16 * 512];   // 64 KB: per-wave frag-packed u
    int w = threadIdx.x >> 6, l = threadIdx.x & 63;
    int m0 = blockIdx.x * 64 + w * 16;
    int arow = m0 + (l & 15);
    short* uw = u_s + w * 16 * 512;
    int R4 = 4 * (l >> 4), c0 = l & 15;

    // GEMM1 in 4 column passes of 128
#pragma unroll
    for (int p = 0; p < 4; p++) {
        f32x4 acc[8];
#pragma unroll
        for (int t = 0; t < 8; t++) acc[t] = {0.f, 0.f, 0.f, 0.f};
#pragma unroll
        for (int kt = 0; kt < 4; kt++) {
            bf16x8 av = load_a(h, arow * DM, kt * 32 + 8 * (l >> 4));
#pragma unroll
            for (int t = 0; t < 8; t++) {
                bf16x8 bv = *reinterpret_cast<const bf16x8*>(pW1 + ((p * 8 + t) * 4 + kt) * 512 + l * 8);
                acc[t] = __builtin_amdgcn_mfma_f32_16x16x32_bf16(av, bv, acc[t], 0, 0, 0);
            }
        }
        // silu + store into frag-packed LDS (A-layout for GEMM2)
#pragma unroll
        for (int t = 0; t < 8; t++) {
            int col = 128 * p + 16 * t + c0;
            float bv1 = b1[col];
            int kt2 = 4 * p + (t >> 1);
            int gp = 2 * (t & 1) + (c0 >> 3);
            int ip = c0 & 7;
#pragma unroll
            for (int r = 0; r < 4; r++) {
                float xv = acc[t][r] + bv1;
                xv = xv / (1.f + __expf(-xv));
                int lp = (R4 + r) + 16 * gp;
                uw[kt2 * 512 + lp * 8 + ip] = f2b(xv);
            }
        }
    }

    // GEMM2: z = u @ W2  (K=512)
    f32x4 acc[8];
#pragma unroll
    for (int t = 0; t < 8; t++) acc[t] = {0.f, 0.f, 0.f, 0.f};
#pragma unroll
    for (int kt = 0; kt < 16; kt++) {
        bf16x8 av = *reinterpret_cast<const bf16x8*>(uw + kt * 512 + l * 8);
#pragma unroll
        for (int t = 0; t < 8; t++) {
            bf16x8 bv = *reinterpret_cast<const bf16x8*>(pW2 + (t * 16 + kt) * 512 + l * 8);
            acc[t] = __builtin_amdgcn_mfma_f32_16x16x32_bf16(av, bv, acc[t], 0, 0, 0);
        }
    }
    // + b2 + residual; LN
#pragma unroll
    for (int t = 0; t < 8; t++) {
        int cc = 16 * t + c0;
        float bv2 = b2[cc];
#pragma unroll
        for (int r = 0; r < 4; r++)
            acc[t][r] += bv2 + h[(m0 + R4 + r) * DM + cc];
    }
    float s[4];
#pragma unroll
    for (int r = 0; r < 4; r++) {
        s[r] = 0.f;
#pragma unroll
        for (int t = 0; t < 8; t++) s[r] += acc[t][r];
    }
#pragma unroll
    for (int m = 1; m < 16; m <<= 1)
#pragma unroll
        for (int r = 0; r < 4; r++) s[r] += __shfl_xor(s[r], m);
    float mean[4];
#pragma unroll
    for (int r = 0; r < 4; r++) mean[r] = s[r] * (1.f / DM);
    float vs[4];
#pragma unroll
    for (int r = 0; r < 4; r++) {
        vs[r] = 0.f;
#pragma unroll
        for (int t = 0; t < 8; t++) {
            float d = acc[t][r] - mean[r];
            vs[r] += d * d;
        }
    }
#pragma unroll
    for (int m = 1; m < 16; m <<= 1)
#pragma unroll
        for (int r = 0; r < 4; r++) vs[r] += __shfl_xor(vs[r], m);
    float inv[4];
#pragma unroll
    for (int r = 0; r < 4; r++) inv[r] = rsqrtf(vs[r] * (1.f / DM) + 1e-5f);
#pragma unroll
    for (int t = 0; t < 8; t++) {
        int cc = 16 * t + c0;
        float gg = g[cc], bbv = bb[cc];
#pragma unroll
        for (int r = 0; r < 4; r++)
            h[(m0 + R4 + r) * DM + cc] = (acc[t][r] - mean[r]) * inv[r] * gg + bbv;
    }
}

// ---------------- masked attention via neighbor lists ----------------
template <bool INTRA>
__global__ __launch_bounds__(256)
void attn_kernel(const float* __restrict__ q, const float* __restrict__ k,
                 const float* __restrict__ v, const float* __restrict__ xw,
                 const u16* __restrict__ idx, const int* __restrict__ cnt,
                 float* __restrict__ o, float* __restrict__ px_part) {
    int gwave = (blockIdx.x * 256 + threadIdx.x) >> 6;
    int lane = threadIdx.x & 63;
    int head = gwave & (NH - 1);
    int i = gwave >> 3;

    float qreg[HD];
    const float* qp = q + i * DM + head * HD;
#pragma unroll
    for (int d = 0; d < HD; d++) qreg[d] = qp[d];

    int n = cnt[i];
    float m = -1e30f, l = 0.f;
    float acc[HD + 3];
#pragma unroll
    for (int d = 0; d < HD + 3; d++) acc[d] = 0.f;

    for (int p = lane; p < n; p += 64) {
        int j = idx[i * CAP + p];
        const float* kp = k + j * DM + head * HD;
        float s = 0.f;
#pragma unroll
        for (int d = 0; d < HD; d++) s += qreg[d] * kp[d];
        s *= 0.25f;
        if (s > m) {
            float corr = __expf(m - s);
            m = s;
            l *= corr;
#pragma unroll
            for (int d = 0; d < HD + 3; d++) acc[d] *= corr;
        }
        float pw = __expf(s - m);
        l += pw;
        const float* vp = v + j * DM + head * HD;
#pragma unroll
        for (int d = 0; d < HD; d++) acc[d] += pw * vp[d];
        if (INTRA) {
            const float* xp = xw + j * 3;
#pragma unroll
            for (int c = 0; c < 3; c++) acc[HD + c] += pw * xp[c];
        }
    }
    float mAll = m;
#pragma unroll
    for (int off = 32; off; off >>= 1) mAll = fmaxf(mAll, __shfl_xor(mAll, off));
    float cf = __expf(m - mAll);
    l *= cf;
#pragma unroll
    for (int d = 0; d < HD + 3; d++) acc[d] *= cf;
#pragma unroll
    for (int off = 32; off; off >>= 1) {
        l += __shfl_xor(l, off);
#pragma unroll
        for (int d = 0; d < HD + 3; d++) acc[d] += __shfl_xor(acc[d], off);
    }
    if (lane == 0) {
        float inv = 1.f / l;
        float* op = o + i * DM + head * HD;
#pragma unroll
        for (int d = 0; d < HD; d++) op[d] = acc[d] * inv;
        if (INTRA) {
            float* pp = px_part + (head * NE + i) * 3;
            pp[0] = acc[HD + 0] * inv;
            pp[1] = acc[HD + 1] * inv;
            pp[2] = acc[HD + 2] * inv;
        }
    }
}

// ---------------- equivariant coordinate update ----------------
__global__ __launch_bounds__(64)
void coord_update(const float* __restrict__ h, const float* __restrict__ Wc,
                  const float* __restrict__ bc, const float* __restrict__ px_part,
                  float* __restrict__ x) {
    int row = blockIdx.x, lane = threadIdx.x;
    float s = h[row * DM + lane] * Wc[lane] +
              h[row * DM + 64 + lane] * Wc[64 + lane];
#pragma unroll
    for (int off = 32; off; off >>= 1) s += __shfl_xor(s, off);
    float gate = tanhf(s + bc[0]);
    if (lane < 3) {
        float px = 0.f;
#pragma unroll
        for (int hh = 0; hh < NH; hh++) px += px_part[(hh * NE + row) * 3 + lane];
        px *= 0.125f;
        float xv = x[row * 3 + lane];
        x[row * 3 + lane] = xv + gate * (xv - px);
    }
}

// ---------------- write outputs (h then x), f32 ----------------
__global__ void finalize_kernel(const float* __restrict__ h, const float* __restrict__ x,
                                float* __restrict__ out) {
    int i = blockIdx.x * blockDim.x + threadIdx.x;
    if (i < NE * DM) out[i] = h[i];
    else if (i < NE * DM + NE * 3) out[i] = x[i - NE * DM];
}

extern "C" void kernel_launch(void* const* d_in, const int* in_sizes, int n_in,
                              void* d_out, int out_size, void* d_ws, size_t ws_size,
                              hipStream_t stream) {
    const float* ef   = (const float*)d_in[0];
    const float* ec   = (const float*)d_in[1];
    const int*   eidx = (const int*)d_in[2];
    const float* nc   = (const float*)d_in[3];
    const int*   bids = (const int*)d_in[4];
    const float* b1   = (const float*)d_in[14];
    const float* b2   = (const float*)d_in[16];
    const float* ln1g = (const float*)d_in[17];
    const float* ln1b = (const float*)d_in[18];
    const float* ln2g = (const float*)d_in[19];
    const float* ln2b = (const float*)d_in[20];
    const float* ln3g = (const float*)d_in[21];
    const float* ln3b = (const float*)d_in[22];
    const float* Wc   = (const float*)d_in[24];
    const float* bc   = (const float*)d_in[25];
    float* out = (float*)d_out;

    // workspace carve — small/critical first
    char* w = (char*)d_ws;
    auto carve = [&](size_t bytes) { char* p = w; w += ((bytes + 255) / 256) * 256; return p; };
    int4*  meta  = (int4*)carve((size_t)NE * 16);
    float* x     = (float*)carve((size_t)NE * 3 * 4);
    float* pxp   = (float*)carve((size_t)NH * NE * 3 * 4);
    int*   cnt_a = (int*)carve((size_t)NE * 4);
    int*   cnt_e = (int*)carve((size_t)NE * 4);
    u16*   idx_a = (u16*)carve((size_t)NE * CAP * 2);
    u16*   idx_e = (u16*)carve((size_t)NE * CAP * 2);
    float* rbf   = (float*)carve((size_t)NE * NR * 4);
    float* h     = (float*)carve((size_t)NE * DM * 4);
    float* o     = (float*)carve((size_t)NE * DM * 4);
    float* q     = (float*)carve((size_t)NE * DM * 4);
    float* k     = (float*)carve((size_t)NE * DM * 4);
    float* v     = (float*)carve((size_t)NE * DM * 4);
    short* pk    = (short*)carve((size_t)NL * PK_LAYER * 2);

    // pack all weights (bf16 fragment layout)
    WSrc ws;
    ws.W[0] = (const float*)d_in[5];   // Wq_a
    ws.W[1] = (const float*)d_in[6];   // Wk_a
    ws.W[2] = (const float*)d_in[7];   // Wv_a
    ws.W[3] = (const float*)d_in[8];   // Wo_a
    ws.W[4] = (const float*)d_in[9];   // Wq_e
    ws.W[5] = (const float*)d_in[10];  // Wk_e
    ws.W[6] = (const float*)d_in[11];  // Wv_e
    ws.W[7] = (const float*)d_in[12];  // Wo_e
    ws.W[8] = (const float*)d_in[13];  // W1
    ws.W[9] = (const float*)d_in[15];  // W2
    ws.W[10] = (const float*)d_in[23]; // Wrbf
    pack_w<<<(NL * PK_LAYER + 255) / 256, 256, 0, stream>>>(ws, pk);

    prep_kernel<<<NE, 64, 0, stream>>>(ef, ec, eidx, nc, bids, h, x, rbf, meta);
    build_lists<<<NE, 64, 0, stream>>>(meta, idx_a, cnt_a, idx_e, cnt_e);

    for (int l = 0; l < NL; l++) {
        const short* Lb = pk + (size_t)l * PK_LAYER;
        // h += rbf @ Wrbf
        gemm_mfma<2, 0><<<dim3(48, 1), 256, 0, stream>>>(rbf, Lb + PK_WRBF, h,
                                                         nullptr, nullptr, nullptr,
                                                         nullptr, nullptr, nullptr);
        // intra MHA
        gemm_mfma<4, 1><<<dim3(48, 3), 256, 0, stream>>>(h, Lb + PK_QKV_A, nullptr,
                                                         nullptr, nullptr, nullptr, q, k, v);
        attn_kernel<true><<<(NH * NE) / 4, 256, 0, stream>>>(q, k, v, x, idx_a, cnt_a, o, pxp);
        gemm_mfma<4, 2><<<dim3(48, 1), 256, 0, stream>>>(o, Lb + PK_WO_A, h, h,
                                                         ln1g + l * DM, ln1b + l * DM,
                                                         nullptr, nullptr, nullptr);
        // inter MHA
        gemm_mfma<4, 1><<<dim3(48, 3), 256, 0, stream>>>(h, Lb + PK_QKV_E, nullptr,
                                                         nullptr, nullptr, nullptr, q, k, v);
        attn_kernel<false><<<(NH * NE) / 4, 256, 0, stream>>>(q, k, v, x, idx_e, cnt_e, o, nullptr);
        gemm_mfma<4, 2><<<dim3(48, 1), 256, 0, stream>>>(o, Lb + PK_WO_E, h, h,
                                                         ln2g + l * DM, ln2b + l * DM,
                                                         nullptr, nullptr, nullptr);
        // FFN
        ffn_mfma<<<48, 256, 0, stream>>>(h, Lb + PK_W1, Lb + PK_W2,
                                         b1 + l * FF, b2 + l * DM,
                                         ln3g + l * DM, ln3b + l * DM);
        // coordinate update
        coord_update<<<NE, 64, 0, stream>>>(h, Wc + l * DM, bc + l, pxp, x);
    }

    int total = NE * DM + NE * 3;
    finalize_kernel<<<(total + 255) / 256, 256, 0, stream>>>(h, x, out);
}